// Round 5
// baseline (149.795 us; speedup 1.0000x reference)
//
#include <hip/hip_runtime.h>
#include <hip/hip_bf16.h>
#include <stdint.h>

#define C_ 64

typedef __bf16   bf16x8 __attribute__((ext_vector_type(8)));
typedef float    f32x4  __attribute__((ext_vector_type(4)));
typedef uint32_t u32x4  __attribute__((ext_vector_type(4)));
typedef unsigned short ush4 __attribute__((ext_vector_type(4)));

__device__ __forceinline__ uint32_t bf16rne(float f) {
    uint32_t u = __float_as_uint(f);
    return (u + 0x7fffu + ((u >> 16) & 1u)) >> 16;
}
__device__ __forceinline__ uint32_t packbf(float lo, float hi) {
    return bf16rne(lo) | (bf16rne(hi) << 16);
}
__device__ __forceinline__ float bf2f(uint32_t bits16) {
    return __uint_as_float(bits16 << 16);
}

// ---------------------------------------------------------------------------
// K1: conv1 via MFMA (unchanged — at its ~96 MB HBM roofline, ~15 us).
// ---------------------------------------------------------------------------
__global__ __launch_bounds__(256, 4) void k_conv1(const float* __restrict__ x,
                                                  const float* __restrict__ w1,
                                                  const float* __restrict__ b1,
                                                  unsigned short* __restrict__ h1) {
    __shared__ u32x4 afrag[512];
    const int t = threadIdx.x;
#pragma unroll
    for (int it = 0; it < 2; ++it) {
        int s  = it * 256 + t;
        int ln = s & 63;
        int o  = 16 * (s >> 7) + (ln & 15);
        int c0 = ((s >> 6) & 1) * 32 + (ln >> 4) * 8;
        const float* wp = w1 + o * 64 + c0;
        float4 f0 = *(const float4*)wp;
        float4 f1 = *(const float4*)(wp + 4);
        u32x4 u; u.x = packbf(f0.x, f0.y); u.y = packbf(f0.z, f0.w);
        u.z = packbf(f1.x, f1.y); u.w = packbf(f1.z, f1.w);
        afrag[s] = u;
    }
    __syncthreads();

    const int lane = t & 63, wv = t >> 6;
    const int q = lane >> 4, l15 = lane & 15;
    const int bid = blockIdx.x;
    const int b   = bid >> 8;
    const int px0 = ((bid & 255) << 8) + wv * 64;
    const size_t planeB = ((size_t)(b * C_)) << 16;

    bf16x8 A[4][2];
#pragma unroll
    for (int mt = 0; mt < 4; ++mt)
#pragma unroll
        for (int ks = 0; ks < 2; ++ks)
            A[mt][ks] = __builtin_bit_cast(bf16x8, afrag[(mt * 2 + ks) * 64 + lane]);

    float b1v[4][4];
#pragma unroll
    for (int mt = 0; mt < 4; ++mt)
#pragma unroll
        for (int r = 0; r < 4; ++r) b1v[mt][r] = b1[16 * mt + q * 4 + r];

#pragma unroll
    for (int nt = 0; nt < 4; ++nt) {
        int px = px0 + nt * 16 + l15;
        bf16x8 Bf[2];
#pragma unroll
        for (int ks = 0; ks < 2; ++ks) {
            const float* xp = x + planeB + (((size_t)(ks * 32 + q * 8)) << 16) + px;
            float v[8];
#pragma unroll
            for (int e = 0; e < 8; ++e) v[e] = xp[(size_t)e << 16];
            u32x4 u; u.x = packbf(v[0], v[1]); u.y = packbf(v[2], v[3]);
            u.z = packbf(v[4], v[5]); u.w = packbf(v[6], v[7]);
            Bf[ks] = __builtin_bit_cast(bf16x8, u);
        }
#pragma unroll
        for (int mt = 0; mt < 4; ++mt) {
            f32x4 acc = {0.f, 0.f, 0.f, 0.f};
            acc = __builtin_amdgcn_mfma_f32_16x16x32_bf16(A[mt][0], Bf[0], acc, 0, 0, 0);
            acc = __builtin_amdgcn_mfma_f32_16x16x32_bf16(A[mt][1], Bf[1], acc, 0, 0, 0);
#pragma unroll
            for (int r = 0; r < 4; ++r) {
                int o = 16 * mt + q * 4 + r;
                h1[planeB + (((size_t)o) << 16) + px] =
                    (unsigned short)bf16rne(acc[r] + b1v[mt][r]);
            }
        }
    }
}

// ---------------------------------------------------------------------------
// K2: barrier-free waves. Wave wv owns block-px slice [16wv,16wv+16); all
// inter-lane traffic is within-wave via LDS (same-wave DS ops are in-order,
// no s_barrier needed). Single __syncthreads after cooperative staging.
// LDS 49,856 B -> 3 blocks/CU:
//   afrag : u32x4[1152]             0 .. 18,432  (wk A-frags, RO after stage)
//   h2p   : u32 [32][68]       18,432 .. 27,136  (h2 bf16 c-pairs)
//   kvt   : u16 [144][68]      27,136 .. 46,720  (predicted kernels)
//   w2s   : f32 [576]          46,720 .. 49,024
//   b2s   : f32 [64]           49,024 .. 49,280
//   bks   : f32 [144]          49,280 .. 49,856
// ---------------------------------------------------------------------------
__global__ __launch_bounds__(256, 3) void k_fused(const float* __restrict__ x,
        const unsigned short* __restrict__ h1,
        const float* __restrict__ w2, const float* __restrict__ b2,
        const float* __restrict__ wk, const float* __restrict__ bk,
        float* __restrict__ out) {
    extern __shared__ char smem[];
    u32x4*    afrag = (u32x4*)smem;
    uint32_t* h2p   = (uint32_t*)(smem + 18432);
    unsigned short* kvt = (unsigned short*)(smem + 27136);
    float*    w2s   = (float*)(smem + 46720);
    float*    b2s   = (float*)(smem + 49024);
    float*    bks   = (float*)(smem + 49280);

    const int t = threadIdx.x;
    int bid = blockIdx.x;
    bid = (bid & 7) * 512 + (bid >> 3);            // XCD swizzle (4096%8==0)
    const int b    = bid >> 10;
    const int rem  = bid & 1023;
    const int hrow = rem >> 2;
    const int w0   = (rem & 3) << 6;
    const size_t planeB = ((size_t)(b * C_)) << 16;

    // ---- Phase A: cooperative staging (single barrier) ----
#pragma unroll
    for (int it = 0; it < 5; ++it) {
        int s = it * 256 + t;
        if (s < 1152) {
            int ln = s & 63;
            int kc = 16 * (s >> 7) + (ln & 15);
            int c0 = ((s >> 6) & 1) * 32 + (ln >> 4) * 8;
            const float* wp = wk + kc * 64 + c0;
            float4 f0 = *(const float4*)wp;
            float4 f1 = *(const float4*)(wp + 4);
            u32x4 u; u.x = packbf(f0.x, f0.y); u.y = packbf(f0.z, f0.w);
            u.z = packbf(f1.x, f1.y); u.w = packbf(f1.z, f1.w);
            afrag[s] = u;
        }
    }
#pragma unroll
    for (int it = 0; it < 3; ++it) {
        int s = it * 256 + t;
        if (s < 576) w2s[s] = w2[s];
    }
    if (t < 64)  b2s[t] = b2[t];
    if (t < 144) bks[t] = bk[t];
    __syncthreads();

    const int lane = t & 63, wv = t >> 6;
    const int cg = lane >> 2, pv = lane & 3;       // 4ch x 4px mapping
    const int i0  = wv * 16 + pv * 4;              // block-local px base
    const int gx0 = w0 + i0;
    const int c0  = cg * 4;

    const int   gxm = (gx0 == 0) ? 0 : gx0 - 1;
    const float mL  = (gx0 == 0) ? 0.f : 1.f;
    const int   gxp = (gx0 + 4 > 255) ? 255 : gx0 + 4;
    const float mR  = (gx0 + 4 > 255) ? 0.f : 1.f;

    float my[3]; int gofs[3];
#pragma unroll
    for (int dy = 0; dy < 3; ++dy) {               // clamp+mask: straight-line
        int gy = hrow + dy - 1;
        my[dy] = ((unsigned)gy < 256u) ? 1.f : 0.f;
        int gyc = gy < 0 ? 0 : (gy > 255 ? 255 : gy);
        gofs[dy] = gyc << 8;
    }

    // ---- Phase B: depthwise 3x3, 4 ch x 4 px (wave's own px slice) ----
    float ah[4][4];
#pragma unroll
    for (int cc = 0; cc < 4; ++cc) {
        int c = c0 + cc;
        float bv = b2s[c];
        float a0 = bv, a1 = bv, a2 = bv, a3 = bv;
        const unsigned short* hp = h1 + planeB + ((size_t)c << 16);
#pragma unroll
        for (int dy = 0; dy < 3; ++dy) {
            const unsigned short* hr = hp + gofs[dy];
            ush4 v = *(const ush4*)(hr + gx0);
            float f0 = bf2f(v[0]), f1 = bf2f(v[1]);
            float f2 = bf2f(v[2]), f3 = bf2f(v[3]);
            float fm = bf2f(hr[gxm]) * mL;
            float fp = bf2f(hr[gxp]) * mR;
            float m  = my[dy];
            float wL = w2s[c * 9 + dy * 3 + 0] * m;
            float wC = w2s[c * 9 + dy * 3 + 1] * m;
            float wR = w2s[c * 9 + dy * 3 + 2] * m;
            a0 = fmaf(fm, wL, fmaf(f0, wC, fmaf(f1, wR, a0)));
            a1 = fmaf(f0, wL, fmaf(f1, wC, fmaf(f2, wR, a1)));
            a2 = fmaf(f1, wL, fmaf(f2, wC, fmaf(f3, wR, a2)));
            a3 = fmaf(f2, wL, fmaf(f3, wC, fmaf(fp, wR, a3)));
        }
        ah[cc][0] = a0; ah[cc][1] = a1; ah[cc][2] = a2; ah[cc][3] = a3;
    }
    {
        int cpb = c0 >> 1;
        u32x4 u0, u1;
#pragma unroll
        for (int p = 0; p < 4; ++p) {
            u0[p] = packbf(ah[0][p], ah[1][p]);
            u1[p] = packbf(ah[2][p], ah[3][p]);
        }
        *(u32x4*)&h2p[(cpb + 0) * 68 + i0] = u0;
        *(u32x4*)&h2p[(cpb + 1) * 68 + i0] = u1;
    }
    // no barrier: same-wave DS RAW is in-order

    // ---- Phase C: MFMA kv[144][wave's 16 px] ----
    const int q = lane >> 4, l15 = lane & 15;
    const int pxr = wv * 16 + l15;
    bf16x8 Bf[2];
#pragma unroll
    for (int ks = 0; ks < 2; ++ks) {
        u32x4 u;
#pragma unroll
        for (int j = 0; j < 4; ++j)
            u[j] = h2p[(ks * 16 + q * 4 + j) * 68 + pxr];
        Bf[ks] = __builtin_bit_cast(bf16x8, u);
    }
    f32x4 acc[9];
#pragma unroll
    for (int mt = 0; mt < 9; ++mt) acc[mt] = (f32x4){0.f, 0.f, 0.f, 0.f};
#pragma unroll
    for (int mt = 0; mt < 9; ++mt) {
        bf16x8 a0 = __builtin_bit_cast(bf16x8, afrag[(mt * 2 + 0) * 64 + lane]);
        acc[mt] = __builtin_amdgcn_mfma_f32_16x16x32_bf16(a0, Bf[0], acc[mt], 0, 0, 0);
        bf16x8 a1 = __builtin_bit_cast(bf16x8, afrag[(mt * 2 + 1) * 64 + lane]);
        acc[mt] = __builtin_amdgcn_mfma_f32_16x16x32_bf16(a1, Bf[1], acc[mt], 0, 0, 0);
    }

    // ---- Phase D: kv + bk -> kvt bf16 [kc][68] (wave's own columns) ----
#pragma unroll
    for (int mt = 0; mt < 9; ++mt) {
        int kc0 = 16 * mt + q * 4;
#pragma unroll
        for (int r = 0; r < 4; ++r) {
            float v = acc[mt][r] + bks[kc0 + r];
            kvt[(kc0 + r) * 68 + pxr] = (unsigned short)bf16rne(v);
        }
    }
    // no barrier: same-wave DS RAW is in-order

    // ---- Phase E: apply predicted 3x3 kernels to x, 4 ch x 4 px ----
    float mLm[3], mRm[3];
#pragma unroll
    for (int dy = 0; dy < 3; ++dy) { mLm[dy] = mL * my[dy]; mRm[dy] = mR * my[dy]; }
#pragma unroll
    for (int cc = 0; cc < 4; ++cc) {
        int c  = c0 + cc;
        int r0 = (9 * c) >> 2;                     // (9c)&3 == c&3 == cc
        ush4 kr0 = *(const ush4*)&kvt[(r0 + 0) * 68 + i0];
        ush4 kr1 = *(const ush4*)&kvt[(r0 + 1) * 68 + i0];
        ush4 kr2 = *(const ush4*)&kvt[(r0 + 2) * 68 + i0];
        float kvf[3][4];
#pragma unroll
        for (int p = 0; p < 4; ++p) {
            kvf[0][p] = bf2f(kr0[p]);
            kvf[1][p] = bf2f(kr1[p]);
            kvf[2][p] = bf2f(kr2[p]);
        }
        const float* xc = x + planeB + ((size_t)c << 16);
        float o[4] = {0.f, 0.f, 0.f, 0.f};
#pragma unroll
        for (int dy = 0; dy < 3; ++dy) {
            const float* xr = xc + gofs[dy];
            float m = my[dy];
            float4 xv = *(const float4*)(xr + gx0);
            float in[6];
            in[0] = xr[gxm] * mLm[dy];
            in[1] = xv.x * m; in[2] = xv.y * m;
            in[3] = xv.z * m; in[4] = xv.w * m;
            in[5] = xr[gxp] * mRm[dy];
#pragma unroll
            for (int tx = 0; tx < 3; ++tx) {
#pragma unroll
                for (int p = 0; p < 4; ++p)
                    o[p] = fmaf(in[p + tx],
                                kvf[(cc + dy * 3 + tx) >> 2][p], o[p]);
            }
        }
        float4 o4 = {o[0], o[1], o[2], o[3]};
        *(float4*)(out + planeB + ((size_t)c << 16) + (hrow << 8) + gx0) = o4;
    }
}

// ---------------------------------------------------------------------------
extern "C" void kernel_launch(void* const* d_in, const int* in_sizes, int n_in,
                              void* d_out, int out_size, void* d_ws, size_t ws_size,
                              hipStream_t stream) {
    const float* x  = (const float*)d_in[0];
    const float* w1 = (const float*)d_in[1];
    const float* b1 = (const float*)d_in[2];
    const float* w2 = (const float*)d_in[3];
    const float* b2 = (const float*)d_in[4];
    const float* wk = (const float*)d_in[5];
    const float* bk = (const float*)d_in[6];
    float* out = (float*)d_out;
    unsigned short* h1 = (unsigned short*)d_ws;    // 32 MB bf16

    k_conv1<<<1024, 256, 0, stream>>>(x, w1, b1, h1);
    hipFuncSetAttribute((const void*)k_fused,
                        hipFuncAttributeMaxDynamicSharedMemorySize, 49856);
    k_fused<<<4096, 256, 49856, stream>>>(x, h1, w2, b2, wk, bk, out);
}

// Round 6
// 98.572 us; speedup vs baseline: 1.5196x; 1.5196x over previous
//
#include <hip/hip_runtime.h>
#include <hip/hip_bf16.h>
#include <stdint.h>

#define C_ 64

typedef __bf16   bf16x8 __attribute__((ext_vector_type(8)));
typedef float    f32x4  __attribute__((ext_vector_type(4)));
typedef uint32_t u32x4  __attribute__((ext_vector_type(4)));
typedef unsigned short ush4 __attribute__((ext_vector_type(4)));

__device__ __forceinline__ uint32_t bf16rne(float f) {
    uint32_t u = __float_as_uint(f);
    return (u + 0x7fffu + ((u >> 16) & 1u)) >> 16;
}
__device__ __forceinline__ uint32_t packbf(float lo, float hi) {
    return bf16rne(lo) | (bf16rne(hi) << 16);
}
__device__ __forceinline__ float bf2f(uint32_t bits16) {
    return __uint_as_float(bits16 << 16);
}

// ---------------------------------------------------------------------------
// K1: conv1 via MFMA (unchanged — at its ~96 MB HBM roofline, ~15 us).
// ---------------------------------------------------------------------------
__global__ __launch_bounds__(256, 4) void k_conv1(const float* __restrict__ x,
                                                  const float* __restrict__ w1,
                                                  const float* __restrict__ b1,
                                                  unsigned short* __restrict__ h1) {
    __shared__ u32x4 afrag[512];
    const int t = threadIdx.x;
#pragma unroll
    for (int it = 0; it < 2; ++it) {
        int s  = it * 256 + t;
        int ln = s & 63;
        int o  = 16 * (s >> 7) + (ln & 15);
        int c0 = ((s >> 6) & 1) * 32 + (ln >> 4) * 8;
        const float* wp = w1 + o * 64 + c0;
        float4 f0 = *(const float4*)wp;
        float4 f1 = *(const float4*)(wp + 4);
        u32x4 u; u.x = packbf(f0.x, f0.y); u.y = packbf(f0.z, f0.w);
        u.z = packbf(f1.x, f1.y); u.w = packbf(f1.z, f1.w);
        afrag[s] = u;
    }
    __syncthreads();

    const int lane = t & 63, wv = t >> 6;
    const int q = lane >> 4, l15 = lane & 15;
    const int bid = blockIdx.x;
    const int b   = bid >> 8;
    const int px0 = ((bid & 255) << 8) + wv * 64;
    const size_t planeB = ((size_t)(b * C_)) << 16;

    bf16x8 A[4][2];
#pragma unroll
    for (int mt = 0; mt < 4; ++mt)
#pragma unroll
        for (int ks = 0; ks < 2; ++ks)
            A[mt][ks] = __builtin_bit_cast(bf16x8, afrag[(mt * 2 + ks) * 64 + lane]);

    float b1v[4][4];
#pragma unroll
    for (int mt = 0; mt < 4; ++mt)
#pragma unroll
        for (int r = 0; r < 4; ++r) b1v[mt][r] = b1[16 * mt + q * 4 + r];

#pragma unroll
    for (int nt = 0; nt < 4; ++nt) {
        int px = px0 + nt * 16 + l15;
        bf16x8 Bf[2];
#pragma unroll
        for (int ks = 0; ks < 2; ++ks) {
            const float* xp = x + planeB + (((size_t)(ks * 32 + q * 8)) << 16) + px;
            float v[8];
#pragma unroll
            for (int e = 0; e < 8; ++e) v[e] = xp[(size_t)e << 16];
            u32x4 u; u.x = packbf(v[0], v[1]); u.y = packbf(v[2], v[3]);
            u.z = packbf(v[4], v[5]); u.w = packbf(v[6], v[7]);
            Bf[ks] = __builtin_bit_cast(bf16x8, u);
        }
#pragma unroll
        for (int mt = 0; mt < 4; ++mt) {
            f32x4 acc = {0.f, 0.f, 0.f, 0.f};
            acc = __builtin_amdgcn_mfma_f32_16x16x32_bf16(A[mt][0], Bf[0], acc, 0, 0, 0);
            acc = __builtin_amdgcn_mfma_f32_16x16x32_bf16(A[mt][1], Bf[1], acc, 0, 0, 0);
#pragma unroll
            for (int r = 0; r < 4; ++r) {
                int o = 16 * mt + q * 4 + r;
                h1[planeB + (((size_t)o) << 16) + px] =
                    (unsigned short)bf16rne(acc[r] + b1v[mt][r]);
            }
        }
    }
}

// ---------------------------------------------------------------------------
// K2: R4 structure + deep load prefetch. LDS 30,272 B -> 5 blocks/CU:
//   afrag : u32x4[1152]            0 .. 18,432   (wk A-frags)
//   h2p   : u32 [32][68]      18,432 .. 27,136   (h2 bf16 c-pairs)
//   w2s   : f32 [576]         27,136 .. 29,440
//   b2s   : f32 [64]          29,440 .. 29,696
//   bks   : f32 [144]         29,696 .. 30,272
//   kvt   : u16 [144][68]  (alias @0; afrag/h2p dead after Phase C barrier)
// Prefetch plan (launch_bounds(256,5) -> ~102 VGPR at same occupancy):
//   h1 taps (48 regs) issued BEFORE staging; x taps cc0-1 before barrier 2,
//   cc2-3 at Phase D top. Rows clamped so loads are unconditional; consume
//   under block-uniform row guards (numerics identical to R4).
// ---------------------------------------------------------------------------
__global__ __launch_bounds__(256, 5) void k_fused(const float* __restrict__ x,
        const unsigned short* __restrict__ h1,
        const float* __restrict__ w2, const float* __restrict__ b2,
        const float* __restrict__ wk, const float* __restrict__ bk,
        float* __restrict__ out) {
    extern __shared__ char smem[];
    u32x4*    afrag = (u32x4*)smem;
    uint32_t* h2p   = (uint32_t*)(smem + 18432);
    float*    w2s   = (float*)(smem + 27136);
    float*    b2s   = (float*)(smem + 29440);
    float*    bks   = (float*)(smem + 29696);
    unsigned short* kvt = (unsigned short*)smem;

    const int t = threadIdx.x;
    int bid = blockIdx.x;
    bid = (bid & 7) * 512 + (bid >> 3);            // XCD swizzle (4096%8==0)
    const int b    = bid >> 10;
    const int rem  = bid & 1023;
    const int hrow = rem >> 2;
    const int w0   = (rem & 3) << 6;
    const size_t planeB = ((size_t)(b * C_)) << 16;

    const int lane = t & 63, wv = t >> 6;
    const int csub = lane >> 4, pg = lane & 15;
    const int px0l = pg << 2;                      // block-local px base
    const int gx0  = w0 + px0l;
    const int c0   = wv * 16 + csub * 4;

    const int   gxm = (gx0 == 0) ? 0 : gx0 - 1;
    const float mL  = (gx0 == 0) ? 0.f : 1.f;
    const int   gxp = (gx0 + 4 > 255) ? 255 : gx0 + 4;
    const float mR  = (gx0 + 4 > 255) ? 0.f : 1.f;

    bool rowok[3]; int gofs[3];
#pragma unroll
    for (int dy = 0; dy < 3; ++dy) {               // clamped rows, uniform guard
        int gy = hrow + dy - 1;
        rowok[dy] = ((unsigned)gy < 256u);
        int gyc = gy < 0 ? 0 : (gy > 255 ? 255 : gy);
        gofs[dy] = gyc << 8;
    }

    // ---- Prefetch: all Phase-B h1 taps (unconditional, clamped rows) ----
    ush4 hq[12]; unsigned short hmv[12], hpv[12];
#pragma unroll
    for (int cc = 0; cc < 4; ++cc) {
        const unsigned short* hc = h1 + planeB + ((size_t)(c0 + cc) << 16);
#pragma unroll
        for (int dy = 0; dy < 3; ++dy) {
            const unsigned short* hr = hc + gofs[dy];
            hq[cc * 3 + dy]  = *(const ush4*)(hr + gx0);
            hmv[cc * 3 + dy] = hr[gxm];
            hpv[cc * 3 + dy] = hr[gxp];
        }
    }

    // ---- Phase A: cooperative staging ----
#pragma unroll
    for (int it = 0; it < 5; ++it) {
        int s = it * 256 + t;
        if (s < 1152) {
            int ln = s & 63;
            int kc = 16 * (s >> 7) + (ln & 15);
            int cb = ((s >> 6) & 1) * 32 + (ln >> 4) * 8;
            const float* wp = wk + kc * 64 + cb;
            float4 f0 = *(const float4*)wp;
            float4 f1 = *(const float4*)(wp + 4);
            u32x4 u; u.x = packbf(f0.x, f0.y); u.y = packbf(f0.z, f0.w);
            u.z = packbf(f1.x, f1.y); u.w = packbf(f1.z, f1.w);
            afrag[s] = u;
        }
    }
#pragma unroll
    for (int it = 0; it < 3; ++it) {
        int s = it * 256 + t;
        if (s < 576) w2s[s] = w2[s];
    }
    if (t < 64)  b2s[t] = b2[t];
    if (t < 144) bks[t] = bk[t];
    __syncthreads();

    // ---- Phase B: depthwise 3x3 from prefetched regs ----
    float ah[4][4];
#pragma unroll
    for (int cc = 0; cc < 4; ++cc) {
        int c = c0 + cc;
        float bv = b2s[c];
        float a0 = bv, a1 = bv, a2 = bv, a3 = bv;
#pragma unroll
        for (int dy = 0; dy < 3; ++dy) {
            if (rowok[dy]) {                       // block-uniform branch
                ush4 v = hq[cc * 3 + dy];
                float f0 = bf2f(v[0]), f1 = bf2f(v[1]);
                float f2 = bf2f(v[2]), f3 = bf2f(v[3]);
                float fm = bf2f(hmv[cc * 3 + dy]) * mL;
                float fp = bf2f(hpv[cc * 3 + dy]) * mR;
                float wL = w2s[c * 9 + dy * 3 + 0];
                float wC = w2s[c * 9 + dy * 3 + 1];
                float wR = w2s[c * 9 + dy * 3 + 2];
                a0 = fmaf(fm, wL, fmaf(f0, wC, fmaf(f1, wR, a0)));
                a1 = fmaf(f0, wL, fmaf(f1, wC, fmaf(f2, wR, a1)));
                a2 = fmaf(f1, wL, fmaf(f2, wC, fmaf(f3, wR, a2)));
                a3 = fmaf(f2, wL, fmaf(f3, wC, fmaf(fp, wR, a3)));
            }
        }
        ah[cc][0] = a0; ah[cc][1] = a1; ah[cc][2] = a2; ah[cc][3] = a3;
    }
    {
        int cpb = c0 >> 1;
        u32x4 u0, u1;
#pragma unroll
        for (int p = 0; p < 4; ++p) {
            u0[p] = packbf(ah[0][p], ah[1][p]);
            u1[p] = packbf(ah[2][p], ah[3][p]);
        }
        *(u32x4*)&h2p[(cpb + 0) * 68 + px0l] = u0;
        *(u32x4*)&h2p[(cpb + 1) * 68 + px0l] = u1;
    }

    // ---- Prefetch x taps for cc = 0,1 (consumed in Phase E) ----
    float4 xq[12];
#pragma unroll
    for (int cc = 0; cc < 2; ++cc) {
        const float* xc = x + planeB + ((size_t)(c0 + cc) << 16);
#pragma unroll
        for (int dy = 0; dy < 3; ++dy)
            xq[cc * 3 + dy] = *(const float4*)(xc + gofs[dy] + gx0);
    }
    __syncthreads();

    // ---- Phase C: MFMA kv[144][16 per wave] ----
    const int q = lane >> 4, l15 = lane & 15;
    const int pxr = wv * 16 + l15;
    bf16x8 Bf[2];
#pragma unroll
    for (int ks = 0; ks < 2; ++ks) {
        u32x4 u;
#pragma unroll
        for (int j = 0; j < 4; ++j)
            u[j] = h2p[(ks * 16 + q * 4 + j) * 68 + pxr];
        Bf[ks] = __builtin_bit_cast(bf16x8, u);
    }
    f32x4 acc[9];
#pragma unroll
    for (int mt = 0; mt < 9; ++mt) acc[mt] = (f32x4){0.f, 0.f, 0.f, 0.f};
#pragma unroll
    for (int mt = 0; mt < 9; ++mt) {
        bf16x8 a0 = __builtin_bit_cast(bf16x8, afrag[(mt * 2 + 0) * 64 + lane]);
        acc[mt] = __builtin_amdgcn_mfma_f32_16x16x32_bf16(a0, Bf[0], acc[mt], 0, 0, 0);
        bf16x8 a1 = __builtin_bit_cast(bf16x8, afrag[(mt * 2 + 1) * 64 + lane]);
        acc[mt] = __builtin_amdgcn_mfma_f32_16x16x32_bf16(a1, Bf[1], acc[mt], 0, 0, 0);
    }
    __syncthreads();                               // afrag + h2p now dead

    // ---- Phase D: prefetch x for cc = 2,3; kv + bk -> kvt bf16 [kc][68] ----
#pragma unroll
    for (int cc = 2; cc < 4; ++cc) {
        const float* xc = x + planeB + ((size_t)(c0 + cc) << 16);
#pragma unroll
        for (int dy = 0; dy < 3; ++dy)
            xq[cc * 3 + dy] = *(const float4*)(xc + gofs[dy] + gx0);
    }
#pragma unroll
    for (int mt = 0; mt < 9; ++mt) {
        int kc0 = 16 * mt + q * 4;
#pragma unroll
        for (int r = 0; r < 4; ++r) {
            float v = acc[mt][r] + bks[kc0 + r];
            kvt[(kc0 + r) * 68 + pxr] = (unsigned short)bf16rne(v);
        }
    }
    __syncthreads();

    // ---- Phase E: apply predicted 3x3 kernels ----
#pragma unroll
    for (int cc = 0; cc < 4; ++cc) {
        int c  = c0 + cc;
        int r0 = (9 * c) >> 2;                     // (9c)&3 == cc
        ush4 kr0 = *(const ush4*)&kvt[(r0 + 0) * 68 + px0l];
        ush4 kr1 = *(const ush4*)&kvt[(r0 + 1) * 68 + px0l];
        ush4 kr2 = *(const ush4*)&kvt[(r0 + 2) * 68 + px0l];
        float kvf[3][4];
#pragma unroll
        for (int p = 0; p < 4; ++p) {
            kvf[0][p] = bf2f(kr0[p]);
            kvf[1][p] = bf2f(kr1[p]);
            kvf[2][p] = bf2f(kr2[p]);
        }
        const float* xc = x + planeB + ((size_t)c << 16);
        float o[4] = {0.f, 0.f, 0.f, 0.f};
#pragma unroll
        for (int dy = 0; dy < 3; ++dy) {
            if (rowok[dy]) {                       // block-uniform branch
                const float* xr = xc + gofs[dy];
                float4 xv = xq[cc * 3 + dy];
                float in[6];
                in[0] = xr[gxm] * mL;              // edge scalars: L1-hot
                in[1] = xv.x; in[2] = xv.y; in[3] = xv.z; in[4] = xv.w;
                in[5] = xr[gxp] * mR;
#pragma unroll
                for (int tx = 0; tx < 3; ++tx) {
#pragma unroll
                    for (int p = 0; p < 4; ++p)
                        o[p] = fmaf(in[p + tx],
                                    kvf[(cc + dy * 3 + tx) >> 2][p], o[p]);
                }
            }
        }
        float4 o4 = {o[0], o[1], o[2], o[3]};
        *(float4*)(out + planeB + ((size_t)c << 16) + (hrow << 8) + gx0) = o4;
    }
}

// ---------------------------------------------------------------------------
extern "C" void kernel_launch(void* const* d_in, const int* in_sizes, int n_in,
                              void* d_out, int out_size, void* d_ws, size_t ws_size,
                              hipStream_t stream) {
    const float* x  = (const float*)d_in[0];
    const float* w1 = (const float*)d_in[1];
    const float* b1 = (const float*)d_in[2];
    const float* w2 = (const float*)d_in[3];
    const float* b2 = (const float*)d_in[4];
    const float* wk = (const float*)d_in[5];
    const float* bk = (const float*)d_in[6];
    float* out = (float*)d_out;
    unsigned short* h1 = (unsigned short*)d_ws;    // 32 MB bf16

    k_conv1<<<1024, 256, 0, stream>>>(x, w1, b1, h1);
    k_fused<<<4096, 256, 30272, stream>>>(x, h1, w2, b2, wk, bk, out);
}

// Round 7
// 89.862 us; speedup vs baseline: 1.6669x; 1.0969x over previous
//
#include <hip/hip_runtime.h>
#include <hip/hip_bf16.h>
#include <stdint.h>

#define C_ 64
#define WS_H1_BYTES 33554432u          // 32 MB bf16 h1
#define WKF_FRAGS 1152                 // 144 kc-rows x (64ch/8) k-chunks... (mt*2+ks)*64+lane

typedef __bf16   bf16x8 __attribute__((ext_vector_type(8)));
typedef float    f32x4  __attribute__((ext_vector_type(4)));
typedef uint32_t u32x4  __attribute__((ext_vector_type(4)));
typedef unsigned short ush4 __attribute__((ext_vector_type(4)));

__device__ __forceinline__ uint32_t bf16rne(float f) {
    uint32_t u = __float_as_uint(f);
    return (u + 0x7fffu + ((u >> 16) & 1u)) >> 16;
}
__device__ __forceinline__ uint32_t packbf(float lo, float hi) {
    return bf16rne(lo) | (bf16rne(hi) << 16);
}
__device__ __forceinline__ float bf2f(uint32_t bits16) {
    return __uint_as_float(bits16 << 16);
}

// ---------------------------------------------------------------------------
// K1: conv1 via MFMA (unchanged — ~HBM roofline, ~15 us).
// ---------------------------------------------------------------------------
__global__ __launch_bounds__(256, 4) void k_conv1(const float* __restrict__ x,
                                                  const float* __restrict__ w1,
                                                  const float* __restrict__ b1,
                                                  unsigned short* __restrict__ h1) {
    __shared__ u32x4 afrag[512];
    const int t = threadIdx.x;
#pragma unroll
    for (int it = 0; it < 2; ++it) {
        int s  = it * 256 + t;
        int ln = s & 63;
        int o  = 16 * (s >> 7) + (ln & 15);
        int c0 = ((s >> 6) & 1) * 32 + (ln >> 4) * 8;
        const float* wp = w1 + o * 64 + c0;
        float4 f0 = *(const float4*)wp;
        float4 f1 = *(const float4*)(wp + 4);
        u32x4 u; u.x = packbf(f0.x, f0.y); u.y = packbf(f0.z, f0.w);
        u.z = packbf(f1.x, f1.y); u.w = packbf(f1.z, f1.w);
        afrag[s] = u;
    }
    __syncthreads();

    const int lane = t & 63, wv = t >> 6;
    const int q = lane >> 4, l15 = lane & 15;
    const int bid = blockIdx.x;
    const int b   = bid >> 8;
    const int px0 = ((bid & 255) << 8) + wv * 64;
    const size_t planeB = ((size_t)(b * C_)) << 16;

    bf16x8 A[4][2];
#pragma unroll
    for (int mt = 0; mt < 4; ++mt)
#pragma unroll
        for (int ks = 0; ks < 2; ++ks)
            A[mt][ks] = __builtin_bit_cast(bf16x8, afrag[(mt * 2 + ks) * 64 + lane]);

    float b1v[4][4];
#pragma unroll
    for (int mt = 0; mt < 4; ++mt)
#pragma unroll
        for (int r = 0; r < 4; ++r) b1v[mt][r] = b1[16 * mt + q * 4 + r];

#pragma unroll
    for (int nt = 0; nt < 4; ++nt) {
        int px = px0 + nt * 16 + l15;
        bf16x8 Bf[2];
#pragma unroll
        for (int ks = 0; ks < 2; ++ks) {
            const float* xp = x + planeB + (((size_t)(ks * 32 + q * 8)) << 16) + px;
            float v[8];
#pragma unroll
            for (int e = 0; e < 8; ++e) v[e] = xp[(size_t)e << 16];
            u32x4 u; u.x = packbf(v[0], v[1]); u.y = packbf(v[2], v[3]);
            u.z = packbf(v[4], v[5]); u.w = packbf(v[6], v[7]);
            Bf[ks] = __builtin_bit_cast(bf16x8, u);
        }
#pragma unroll
        for (int mt = 0; mt < 4; ++mt) {
            f32x4 acc = {0.f, 0.f, 0.f, 0.f};
            acc = __builtin_amdgcn_mfma_f32_16x16x32_bf16(A[mt][0], Bf[0], acc, 0, 0, 0);
            acc = __builtin_amdgcn_mfma_f32_16x16x32_bf16(A[mt][1], Bf[1], acc, 0, 0, 0);
#pragma unroll
            for (int r = 0; r < 4; ++r) {
                int o = 16 * mt + q * 4 + r;
                h1[planeB + (((size_t)o) << 16) + px] =
                    (unsigned short)bf16rne(acc[r] + b1v[mt][r]);
            }
        }
    }
}

// ---------------------------------------------------------------------------
// k_pack: pre-pack wk (fp32 [144][64]) into bf16 MFMA A-fragments, once.
// wkf[s], s = (mt*2+ks)*64 + lane; 1152 u32x4 = 18,432 B. Idempotent.
// ---------------------------------------------------------------------------
__global__ __launch_bounds__(256) void k_pack(const float* __restrict__ wk,
                                              u32x4* __restrict__ wkf) {
    int s = blockIdx.x * 256 + threadIdx.x;
    if (s < WKF_FRAGS) {
        int ln = s & 63;
        int kc = 16 * (s >> 7) + (ln & 15);
        int cb = ((s >> 6) & 1) * 32 + (ln >> 4) * 8;
        const float* wp = wk + kc * 64 + cb;
        float4 f0 = *(const float4*)wp;
        float4 f1 = *(const float4*)(wp + 4);
        u32x4 u; u.x = packbf(f0.x, f0.y); u.y = packbf(f0.z, f0.w);
        u.z = packbf(f1.x, f1.y); u.w = packbf(f1.z, f1.w);
        wkf[s] = u;
    }
}

// ---------------------------------------------------------------------------
// K2 (pre-packed): occupancy-first. LDS 22,720 B -> not the cap; waves capped
// by __launch_bounds__(256,6) -> 24 waves/CU (vs 20 before).
//   afragL : u32x4[640]             0 .. 10,240  (wk frags mt=0..4 only)
//   h2p    : u32 [32][68]      10,240 .. 18,944
//   kvt    : u16 [144][68]  alias @0 .. 19,584  (afragL/h2p dead by then)
//   w2s/b2s/bks                19,584 .. 22,720
// Frags mt=5..8 load straight from wkf (L2-hot) into 32 VGPRs at phase-C top,
// latency hidden under the mt0-4 LDS-MFMA chain.
// ---------------------------------------------------------------------------
__global__ __launch_bounds__(256, 6) void k_fused_pre(const float* __restrict__ x,
        const unsigned short* __restrict__ h1, const u32x4* __restrict__ wkf,
        const float* __restrict__ w2, const float* __restrict__ b2,
        const float* __restrict__ bk, float* __restrict__ out) {
    extern __shared__ char smem[];
    u32x4*    afragL = (u32x4*)smem;                 // [640]
    uint32_t* h2p    = (uint32_t*)(smem + 10240);    // [32][68]
    unsigned short* kvt = (unsigned short*)smem;     // [144][68] alias
    float* w2s = (float*)(smem + 19584);
    float* b2s = (float*)(smem + 21888);
    float* bks = (float*)(smem + 22144);

    const int t = threadIdx.x;
    int bid = blockIdx.x;
    bid = (bid & 7) * 512 + (bid >> 3);              // XCD swizzle (4096%8==0)
    const int b    = bid >> 10;
    const int rem  = bid & 1023;
    const int hrow = rem >> 2;
    const int w0   = (rem & 3) << 6;
    const size_t planeB = ((size_t)(b * C_)) << 16;

    const int lane = t & 63, wv = t >> 6;
    const int csub = lane >> 4, pg = lane & 15;
    const int px0l = pg << 2;
    const int gx0  = w0 + px0l;
    const int c0   = wv * 16 + csub * 4;

    const int   gxm = (gx0 == 0) ? 0 : gx0 - 1;
    const float mL  = (gx0 == 0) ? 0.f : 1.f;
    const int   gxp = (gx0 + 4 > 255) ? 255 : gx0 + 4;
    const float mR  = (gx0 + 4 > 255) ? 0.f : 1.f;

    bool rowok[3]; int gofs[3];
#pragma unroll
    for (int dy = 0; dy < 3; ++dy) {
        int gy = hrow + dy - 1;
        rowok[dy] = ((unsigned)gy < 256u);
        int gyc = gy < 0 ? 0 : (gy > 255 ? 255 : gy);
        gofs[dy] = gyc << 8;
    }

    // ---- prefetch h1 taps for cc = 0,1 (drain hides under staging) ----
    ush4 hq[6]; unsigned short hmv[6], hpv[6];
#pragma unroll
    for (int cc = 0; cc < 2; ++cc) {
        const unsigned short* hc = h1 + planeB + ((size_t)(c0 + cc) << 16);
#pragma unroll
        for (int dy = 0; dy < 3; ++dy) {
            const unsigned short* hr = hc + gofs[dy];
            hq[cc * 3 + dy]  = *(const ush4*)(hr + gx0);
            hmv[cc * 3 + dy] = hr[gxm];
            hpv[cc * 3 + dy] = hr[gxp];
        }
    }

    // ---- Phase A: stage afragL (plain u32x4 copies) + biases ----
#pragma unroll
    for (int it = 0; it < 3; ++it) {
        int s = it * 256 + t;
        if (s < 640) afragL[s] = wkf[s];
    }
#pragma unroll
    for (int it = 0; it < 3; ++it) {
        int s = it * 256 + t;
        if (s < 576) w2s[s] = w2[s];
    }
    if (t < 64)  b2s[t] = b2[t];
    if (t < 144) bks[t] = bk[t];
    __syncthreads();

    // ---- Phase B: dw 3x3; cc2-3 loads issued first, cc0-1 from regs ----
    ush4 hq2[6]; unsigned short hmv2[6], hpv2[6];
#pragma unroll
    for (int cc = 2; cc < 4; ++cc) {
        const unsigned short* hc = h1 + planeB + ((size_t)(c0 + cc) << 16);
#pragma unroll
        for (int dy = 0; dy < 3; ++dy) {
            const unsigned short* hr = hc + gofs[dy];
            hq2[(cc - 2) * 3 + dy]  = *(const ush4*)(hr + gx0);
            hmv2[(cc - 2) * 3 + dy] = hr[gxm];
            hpv2[(cc - 2) * 3 + dy] = hr[gxp];
        }
    }
    float ah[4][4];
#pragma unroll
    for (int cc = 0; cc < 4; ++cc) {
        int c = c0 + cc;
        float bv = b2s[c];
        float a0 = bv, a1 = bv, a2 = bv, a3 = bv;
#pragma unroll
        for (int dy = 0; dy < 3; ++dy) {
            if (rowok[dy]) {
                ush4 v; float fm, fp;
                if (cc < 2) { v = hq[cc * 3 + dy];
                              fm = bf2f(hmv[cc * 3 + dy]) * mL;
                              fp = bf2f(hpv[cc * 3 + dy]) * mR; }
                else        { v = hq2[(cc - 2) * 3 + dy];
                              fm = bf2f(hmv2[(cc - 2) * 3 + dy]) * mL;
                              fp = bf2f(hpv2[(cc - 2) * 3 + dy]) * mR; }
                float f0 = bf2f(v[0]), f1 = bf2f(v[1]);
                float f2 = bf2f(v[2]), f3 = bf2f(v[3]);
                float wL = w2s[c * 9 + dy * 3 + 0];
                float wC = w2s[c * 9 + dy * 3 + 1];
                float wR = w2s[c * 9 + dy * 3 + 2];
                a0 = fmaf(fm, wL, fmaf(f0, wC, fmaf(f1, wR, a0)));
                a1 = fmaf(f0, wL, fmaf(f1, wC, fmaf(f2, wR, a1)));
                a2 = fmaf(f1, wL, fmaf(f2, wC, fmaf(f3, wR, a2)));
                a3 = fmaf(f2, wL, fmaf(f3, wC, fmaf(fp, wR, a3)));
            }
        }
        ah[cc][0] = a0; ah[cc][1] = a1; ah[cc][2] = a2; ah[cc][3] = a3;
    }
    {
        int cpb = c0 >> 1;
        u32x4 u0, u1;
#pragma unroll
        for (int p = 0; p < 4; ++p) {
            u0[p] = packbf(ah[0][p], ah[1][p]);
            u1[p] = packbf(ah[2][p], ah[3][p]);
        }
        *(u32x4*)&h2p[(cpb + 0) * 68 + px0l] = u0;
        *(u32x4*)&h2p[(cpb + 1) * 68 + px0l] = u1;
    }
    __syncthreads();

    // ---- Phase C: MFMA. mt0-4 from LDS; mt5-8 from global-loaded regs ----
    const int q = lane >> 4, l15 = lane & 15;
    const int pxr = wv * 16 + l15;
    u32x4 Areg[8];
#pragma unroll
    for (int f = 0; f < 8; ++f) Areg[f] = wkf[640 + f * 64 + lane];
    bf16x8 Bf[2];
#pragma unroll
    for (int ks = 0; ks < 2; ++ks) {
        u32x4 u;
#pragma unroll
        for (int j = 0; j < 4; ++j)
            u[j] = h2p[(ks * 16 + q * 4 + j) * 68 + pxr];
        Bf[ks] = __builtin_bit_cast(bf16x8, u);
    }
    f32x4 acc[9];
#pragma unroll
    for (int mt = 0; mt < 9; ++mt) acc[mt] = (f32x4){0.f, 0.f, 0.f, 0.f};
#pragma unroll
    for (int mt = 0; mt < 5; ++mt) {
        bf16x8 a0 = __builtin_bit_cast(bf16x8, afragL[(mt * 2 + 0) * 64 + lane]);
        acc[mt] = __builtin_amdgcn_mfma_f32_16x16x32_bf16(a0, Bf[0], acc[mt], 0, 0, 0);
        bf16x8 a1 = __builtin_bit_cast(bf16x8, afragL[(mt * 2 + 1) * 64 + lane]);
        acc[mt] = __builtin_amdgcn_mfma_f32_16x16x32_bf16(a1, Bf[1], acc[mt], 0, 0, 0);
    }
#pragma unroll
    for (int mt = 5; mt < 9; ++mt) {
        acc[mt] = __builtin_amdgcn_mfma_f32_16x16x32_bf16(
            __builtin_bit_cast(bf16x8, Areg[(mt - 5) * 2 + 0]), Bf[0], acc[mt], 0, 0, 0);
        acc[mt] = __builtin_amdgcn_mfma_f32_16x16x32_bf16(
            __builtin_bit_cast(bf16x8, Areg[(mt - 5) * 2 + 1]), Bf[1], acc[mt], 0, 0, 0);
    }
    __syncthreads();                                 // afragL + h2p now dead

    // ---- Phase D: kv + bk -> kvt; prefetch x taps for cc=0 ----
    float4 xq[2][3]; float xmv_[2][3], xpv_[2][3];
    {
        const float* xc = x + planeB + ((size_t)c0 << 16);
#pragma unroll
        for (int dy = 0; dy < 3; ++dy) {
            const float* xr = xc + gofs[dy];
            xq[0][dy] = *(const float4*)(xr + gx0);
            xmv_[0][dy] = xr[gxm]; xpv_[0][dy] = xr[gxp];
        }
    }
#pragma unroll
    for (int mt = 0; mt < 9; ++mt) {
        int kc0 = 16 * mt + q * 4;
#pragma unroll
        for (int r = 0; r < 4; ++r) {
            float v = acc[mt][r] + bks[kc0 + r];
            kvt[(kc0 + r) * 68 + pxr] = (unsigned short)bf16rne(v);
        }
    }
    __syncthreads();

    // ---- Phase E: apply, x-tap loads rotated one cc ahead ----
#pragma unroll
    for (int cc = 0; cc < 4; ++cc) {
        if (cc < 3) {                                // prefetch next cc
            const float* xc = x + planeB + ((size_t)(c0 + cc + 1) << 16);
#pragma unroll
            for (int dy = 0; dy < 3; ++dy) {
                const float* xr = xc + gofs[dy];
                xq[(cc + 1) & 1][dy] = *(const float4*)(xr + gx0);
                xmv_[(cc + 1) & 1][dy] = xr[gxm];
                xpv_[(cc + 1) & 1][dy] = xr[gxp];
            }
        }
        int c  = c0 + cc;
        int r0 = (9 * c) >> 2;                       // (9c)&3 == cc
        ush4 kr0 = *(const ush4*)&kvt[(r0 + 0) * 68 + px0l];
        ush4 kr1 = *(const ush4*)&kvt[(r0 + 1) * 68 + px0l];
        ush4 kr2 = *(const ush4*)&kvt[(r0 + 2) * 68 + px0l];
        float kvf[3][4];
#pragma unroll
        for (int p = 0; p < 4; ++p) {
            kvf[0][p] = bf2f(kr0[p]);
            kvf[1][p] = bf2f(kr1[p]);
            kvf[2][p] = bf2f(kr2[p]);
        }
        float o[4] = {0.f, 0.f, 0.f, 0.f};
#pragma unroll
        for (int dy = 0; dy < 3; ++dy) {
            if (rowok[dy]) {
                float4 xv = xq[cc & 1][dy];
                float in[6];
                in[0] = xmv_[cc & 1][dy] * mL;
                in[1] = xv.x; in[2] = xv.y; in[3] = xv.z; in[4] = xv.w;
                in[5] = xpv_[cc & 1][dy] * mR;
#pragma unroll
                for (int tx = 0; tx < 3; ++tx) {
#pragma unroll
                    for (int p = 0; p < 4; ++p)
                        o[p] = fmaf(in[p + tx],
                                    kvf[(cc + dy * 3 + tx) >> 2][p], o[p]);
                }
            }
        }
        float4 o4 = {o[0], o[1], o[2], o[3]};
        *(float4*)(out + planeB + ((size_t)c << 16) + (hrow << 8) + gx0) = o4;
    }
}

// ---------------------------------------------------------------------------
// Fallback (ws too small for wkf): R6 kernel verbatim. LDS 30,272 B.
// ---------------------------------------------------------------------------
__global__ __launch_bounds__(256, 5) void k_fused_fb(const float* __restrict__ x,
        const unsigned short* __restrict__ h1,
        const float* __restrict__ w2, const float* __restrict__ b2,
        const float* __restrict__ wk, const float* __restrict__ bk,
        float* __restrict__ out) {
    extern __shared__ char smem[];
    u32x4*    afrag = (u32x4*)smem;
    uint32_t* h2p   = (uint32_t*)(smem + 18432);
    float*    w2s   = (float*)(smem + 27136);
    float*    b2s   = (float*)(smem + 29440);
    float*    bks   = (float*)(smem + 29696);
    unsigned short* kvt = (unsigned short*)smem;

    const int t = threadIdx.x;
    int bid = blockIdx.x;
    bid = (bid & 7) * 512 + (bid >> 3);
    const int b    = bid >> 10;
    const int rem  = bid & 1023;
    const int hrow = rem >> 2;
    const int w0   = (rem & 3) << 6;
    const size_t planeB = ((size_t)(b * C_)) << 16;

    const int lane = t & 63, wv = t >> 6;
    const int csub = lane >> 4, pg = lane & 15;
    const int px0l = pg << 2;
    const int gx0  = w0 + px0l;
    const int c0   = wv * 16 + csub * 4;

    const int   gxm = (gx0 == 0) ? 0 : gx0 - 1;
    const float mL  = (gx0 == 0) ? 0.f : 1.f;
    const int   gxp = (gx0 + 4 > 255) ? 255 : gx0 + 4;
    const float mR  = (gx0 + 4 > 255) ? 0.f : 1.f;

    bool rowok[3]; int gofs[3];
#pragma unroll
    for (int dy = 0; dy < 3; ++dy) {
        int gy = hrow + dy - 1;
        rowok[dy] = ((unsigned)gy < 256u);
        int gyc = gy < 0 ? 0 : (gy > 255 ? 255 : gy);
        gofs[dy] = gyc << 8;
    }

    ush4 hq[12]; unsigned short hmv[12], hpv[12];
#pragma unroll
    for (int cc = 0; cc < 4; ++cc) {
        const unsigned short* hc = h1 + planeB + ((size_t)(c0 + cc) << 16);
#pragma unroll
        for (int dy = 0; dy < 3; ++dy) {
            const unsigned short* hr = hc + gofs[dy];
            hq[cc * 3 + dy]  = *(const ush4*)(hr + gx0);
            hmv[cc * 3 + dy] = hr[gxm];
            hpv[cc * 3 + dy] = hr[gxp];
        }
    }

#pragma unroll
    for (int it = 0; it < 5; ++it) {
        int s = it * 256 + t;
        if (s < 1152) {
            int ln = s & 63;
            int kc = 16 * (s >> 7) + (ln & 15);
            int cb = ((s >> 6) & 1) * 32 + (ln >> 4) * 8;
            const float* wp = wk + kc * 64 + cb;
            float4 f0 = *(const float4*)wp;
            float4 f1 = *(const float4*)(wp + 4);
            u32x4 u; u.x = packbf(f0.x, f0.y); u.y = packbf(f0.z, f0.w);
            u.z = packbf(f1.x, f1.y); u.w = packbf(f1.z, f1.w);
            afrag[s] = u;
        }
    }
#pragma unroll
    for (int it = 0; it < 3; ++it) {
        int s = it * 256 + t;
        if (s < 576) w2s[s] = w2[s];
    }
    if (t < 64)  b2s[t] = b2[t];
    if (t < 144) bks[t] = bk[t];
    __syncthreads();

    float ah[4][4];
#pragma unroll
    for (int cc = 0; cc < 4; ++cc) {
        int c = c0 + cc;
        float bv = b2s[c];
        float a0 = bv, a1 = bv, a2 = bv, a3 = bv;
#pragma unroll
        for (int dy = 0; dy < 3; ++dy) {
            if (rowok[dy]) {
                ush4 v = hq[cc * 3 + dy];
                float f0 = bf2f(v[0]), f1 = bf2f(v[1]);
                float f2 = bf2f(v[2]), f3 = bf2f(v[3]);
                float fm = bf2f(hmv[cc * 3 + dy]) * mL;
                float fp = bf2f(hpv[cc * 3 + dy]) * mR;
                float wL = w2s[c * 9 + dy * 3 + 0];
                float wC = w2s[c * 9 + dy * 3 + 1];
                float wR = w2s[c * 9 + dy * 3 + 2];
                a0 = fmaf(fm, wL, fmaf(f0, wC, fmaf(f1, wR, a0)));
                a1 = fmaf(f0, wL, fmaf(f1, wC, fmaf(f2, wR, a1)));
                a2 = fmaf(f1, wL, fmaf(f2, wC, fmaf(f3, wR, a2)));
                a3 = fmaf(f2, wL, fmaf(f3, wC, fmaf(fp, wR, a3)));
            }
        }
        ah[cc][0] = a0; ah[cc][1] = a1; ah[cc][2] = a2; ah[cc][3] = a3;
    }
    {
        int cpb = c0 >> 1;
        u32x4 u0, u1;
#pragma unroll
        for (int p = 0; p < 4; ++p) {
            u0[p] = packbf(ah[0][p], ah[1][p]);
            u1[p] = packbf(ah[2][p], ah[3][p]);
        }
        *(u32x4*)&h2p[(cpb + 0) * 68 + px0l] = u0;
        *(u32x4*)&h2p[(cpb + 1) * 68 + px0l] = u1;
    }

    float4 xq[12];
#pragma unroll
    for (int cc = 0; cc < 2; ++cc) {
        const float* xc = x + planeB + ((size_t)(c0 + cc) << 16);
#pragma unroll
        for (int dy = 0; dy < 3; ++dy)
            xq[cc * 3 + dy] = *(const float4*)(xc + gofs[dy] + gx0);
    }
    __syncthreads();

    const int q = lane >> 4, l15 = lane & 15;
    const int pxr = wv * 16 + l15;
    bf16x8 Bf[2];
#pragma unroll
    for (int ks = 0; ks < 2; ++ks) {
        u32x4 u;
#pragma unroll
        for (int j = 0; j < 4; ++j)
            u[j] = h2p[(ks * 16 + q * 4 + j) * 68 + pxr];
        Bf[ks] = __builtin_bit_cast(bf16x8, u);
    }
    f32x4 acc[9];
#pragma unroll
    for (int mt = 0; mt < 9; ++mt) acc[mt] = (f32x4){0.f, 0.f, 0.f, 0.f};
#pragma unroll
    for (int mt = 0; mt < 9; ++mt) {
        bf16x8 a0 = __builtin_bit_cast(bf16x8, afrag[(mt * 2 + 0) * 64 + lane]);
        acc[mt] = __builtin_amdgcn_mfma_f32_16x16x32_bf16(a0, Bf[0], acc[mt], 0, 0, 0);
        bf16x8 a1 = __builtin_bit_cast(bf16x8, afrag[(mt * 2 + 1) * 64 + lane]);
        acc[mt] = __builtin_amdgcn_mfma_f32_16x16x32_bf16(a1, Bf[1], acc[mt], 0, 0, 0);
    }
    __syncthreads();

#pragma unroll
    for (int cc = 2; cc < 4; ++cc) {
        const float* xc = x + planeB + ((size_t)(c0 + cc) << 16);
#pragma unroll
        for (int dy = 0; dy < 3; ++dy)
            xq[cc * 3 + dy] = *(const float4*)(xc + gofs[dy] + gx0);
    }
#pragma unroll
    for (int mt = 0; mt < 9; ++mt) {
        int kc0 = 16 * mt + q * 4;
#pragma unroll
        for (int r = 0; r < 4; ++r) {
            float v = acc[mt][r] + bks[kc0 + r];
            kvt[(kc0 + r) * 68 + pxr] = (unsigned short)bf16rne(v);
        }
    }
    __syncthreads();

#pragma unroll
    for (int cc = 0; cc < 4; ++cc) {
        int c  = c0 + cc;
        int r0 = (9 * c) >> 2;
        ush4 kr0 = *(const ush4*)&kvt[(r0 + 0) * 68 + px0l];
        ush4 kr1 = *(const ush4*)&kvt[(r0 + 1) * 68 + px0l];
        ush4 kr2 = *(const ush4*)&kvt[(r0 + 2) * 68 + px0l];
        float kvf[3][4];
#pragma unroll
        for (int p = 0; p < 4; ++p) {
            kvf[0][p] = bf2f(kr0[p]);
            kvf[1][p] = bf2f(kr1[p]);
            kvf[2][p] = bf2f(kr2[p]);
        }
        const float* xc = x + planeB + ((size_t)c << 16);
        float o[4] = {0.f, 0.f, 0.f, 0.f};
#pragma unroll
        for (int dy = 0; dy < 3; ++dy) {
            if (rowok[dy]) {
                const float* xr = xc + gofs[dy];
                float4 xv = xq[cc * 3 + dy];
                float in[6];
                in[0] = xr[gxm] * mL;
                in[1] = xv.x; in[2] = xv.y; in[3] = xv.z; in[4] = xv.w;
                in[5] = xr[gxp] * mR;
#pragma unroll
                for (int tx = 0; tx < 3; ++tx) {
#pragma unroll
                    for (int p = 0; p < 4; ++p)
                        o[p] = fmaf(in[p + tx],
                                    kvf[(cc + dy * 3 + tx) >> 2][p], o[p]);
                }
            }
        }
        float4 o4 = {o[0], o[1], o[2], o[3]};
        *(float4*)(out + planeB + ((size_t)c << 16) + (hrow << 8) + gx0) = o4;
    }
}

// ---------------------------------------------------------------------------
extern "C" void kernel_launch(void* const* d_in, const int* in_sizes, int n_in,
                              void* d_out, int out_size, void* d_ws, size_t ws_size,
                              hipStream_t stream) {
    const float* x  = (const float*)d_in[0];
    const float* w1 = (const float*)d_in[1];
    const float* b1 = (const float*)d_in[2];
    const float* w2 = (const float*)d_in[3];
    const float* b2 = (const float*)d_in[4];
    const float* wk = (const float*)d_in[5];
    const float* bk = (const float*)d_in[6];
    float* out = (float*)d_out;
    unsigned short* h1 = (unsigned short*)d_ws;      // 32 MB bf16

    const size_t need = (size_t)WS_H1_BYTES + WKF_FRAGS * sizeof(u32x4);
    if (ws_size >= need) {
        u32x4* wkf = (u32x4*)((char*)d_ws + WS_H1_BYTES);
        k_pack<<<(WKF_FRAGS + 255) / 256, 256, 0, stream>>>(wk, wkf);
        k_conv1<<<1024, 256, 0, stream>>>(x, w1, b1, h1);
        k_fused_pre<<<4096, 256, 22720, stream>>>(x, h1, wkf, w2, b2, bk, out);
    } else {
        k_conv1<<<1024, 256, 0, stream>>>(x, w1, b1, h1);
        k_fused_fb<<<4096, 256, 30272, stream>>>(x, h1, w2, b2, wk, bk, out);
    }
}